// Round 9
// baseline (348.062 us; speedup 1.0000x reference)
//
#include <hip/hip_runtime.h>

#define HID 256
#define NFEAT 9
#define VOCAB 119
#define NLAYERS 4
#define NGRAPHS 256
#define BN_EPS 1e-5f
#define MAGIC1 0x13572468u
#define MAGIC2 0x24681357u

typedef short short8 __attribute__((ext_vector_type(8)));
typedef float floatx4 __attribute__((ext_vector_type(4)));

__device__ inline unsigned short f2bf(float f) {
    unsigned int u = __float_as_uint(f);
    unsigned int r = u + 0x7FFF + ((u >> 16) & 1);  // RNE
    return (unsigned short)(r >> 16);
}
__device__ inline float bf2f(unsigned short u) {
    return __uint_as_float(((unsigned int)u) << 16);
}

__device__ inline unsigned int agent_load(const unsigned int* p) {
    return __hip_atomic_load(p, __ATOMIC_RELAXED, __HIP_MEMORY_SCOPE_AGENT);
}
__device__ inline int agent_load_i(const int* p) {
    return __hip_atomic_load(p, __ATOMIC_RELAXED, __HIP_MEMORY_SCOPE_AGENT);
}
// bounded spin (bailout prevents harness hang on logic error; absmax would catch)
__device__ inline void spin_until(const unsigned int* p, unsigned int tgt) {
    for (int k = 0; k < (1 << 24); ++k) {
        if (agent_load(p) == tgt) return;
        __builtin_amdgcn_s_sleep(2);
    }
}

// =================== mega setup kernel ===================
// One dispatch replaces zero/deg/scan/fill/wcvt/embed (6 -> 1).
// Roles by blockIdx (producers first => resident first; in-order dispatch):
//   [0]                   zero degi/fillc/bnsums, fence, set ctrl[0]=MAGIC1
//   [1 .. nbDeg]          deg: spin MAGIC1, atomicAdd degi (LLC), block-done++ -> ctrl[1]
//   [wcvtBase .. +256)    weight transpose+cvt (independent)
//   [embBase .. +N)       atom-encoder embed (independent)
//   [scanIdx]             spin ctrl[1]==nbDeg, scan degi (agent loads), write row_ptr/nrm,
//                         threadfence (wbL2), set ctrl[2]=MAGIC2
//   [fillBase .. +nbDeg)  spin MAGIC2, CSR fill (fillc via LLC atomics)
__global__ __launch_bounds__(256) void mega_setup(
        const int* __restrict__ x, const int* __restrict__ ei,
        const float* __restrict__ emb, const float* __restrict__ W,
        unsigned int* __restrict__ ctrl, int* __restrict__ degi,
        int* __restrict__ row_ptr, int* __restrict__ fillc,
        float* __restrict__ nrm, int2* __restrict__ edges,
        unsigned short* __restrict__ wt, unsigned short* __restrict__ hbA,
        float* __restrict__ bnsums,
        int N, int E, int nbDeg, int wcvtBase, int embBase, int scanIdx, int fillBase) {
    const int bx = blockIdx.x;
    const int tid = threadIdx.x;
    const int* srcp = ei;
    const int* dstp = ei + E;

    __shared__ float sw[32][33];
    __shared__ int xf[NFEAT];
    __shared__ int ws4[4];

    if (bx == 0) {
        // ---- zero role ----
        for (int i = tid; i < N; i += 256) { degi[i] = 0; fillc[i] = 0; }
        for (int i = tid; i < NLAYERS * 2 * HID; i += 256) bnsums[i] = 0.f;
        __syncthreads();
        if (tid == 0) {
            __threadfence();                       // push zeros to LLC
            __hip_atomic_store(&ctrl[0], MAGIC1, __ATOMIC_RELAXED, __HIP_MEMORY_SCOPE_AGENT);
        }
    } else if (bx <= nbDeg) {
        // ---- deg role ----
        if (tid == 0) spin_until(&ctrl[0], MAGIC1);
        __syncthreads();
        int i = (bx - 1) * 256 + tid;
        if (i < E) atomicAdd(&degi[dstp[i]], 1);   // device-scope -> LLC
        __syncthreads();                           // drains vmcnt: atomics complete
        if (tid == 0) atomicAdd(&ctrl[1], 1u);
    } else if (bx < embBase) {
        // ---- wcvt role: Wt[l][n][k] ----
        int j = bx - wcvtBase;
        int l = j >> 6;
        int rem = j & 63;
        int k0 = (rem >> 3) * 32, n0 = (rem & 7) * 32;
        int c = tid & 31, r8 = tid >> 5;
        const float* Wl = W + (size_t)l * HID * HID;
        unsigned short* Wtl = wt + (size_t)l * HID * HID;
#pragma unroll
        for (int p = 0; p < 4; ++p) {
            int r = r8 + p * 8;
            sw[r][c] = Wl[(k0 + r) * HID + n0 + c];
        }
        __syncthreads();
#pragma unroll
        for (int p = 0; p < 4; ++p) {
            int r = r8 + p * 8;
            Wtl[(size_t)(n0 + r) * HID + k0 + c] = f2bf(sw[c][r]);
        }
    } else if (bx < scanIdx) {
        // ---- embed role ----
        int n = bx - embBase;
        if (tid < NFEAT) xf[tid] = x[n * NFEAT + tid];
        __syncthreads();
        float s = 0.f;
#pragma unroll
        for (int f = 0; f < NFEAT; ++f) s += emb[(size_t)(f * VOCAB + xf[f]) * HID + tid];
        hbA[(size_t)n * HID + tid] = f2bf(s);
    } else if (bx == scanIdx) {
        // ---- scan role (single block, 256 thr) ----
        if (tid == 0) spin_until(&ctrl[1], (unsigned int)nbDeg);
        __syncthreads();
        int ch = (N + 255) >> 8;
        int i0 = min(tid * ch, N), i1 = min(i0 + ch, N);
        int local = 0;
        for (int i = i0; i < i1; ++i) local += agent_load_i(&degi[i]);
        int lane = tid & 63, wid = tid >> 6;
        int v = local;
#pragma unroll
        for (int off = 1; off < 64; off <<= 1) {
            int u = __shfl_up(v, off);
            if (lane >= off) v += u;
        }
        if (lane == 63) ws4[wid] = v;
        __syncthreads();
        if (tid == 0) { ws4[1] += ws4[0]; ws4[2] += ws4[1]; ws4[3] += ws4[2]; }
        __syncthreads();
        int run = (wid > 0 ? ws4[wid - 1] : 0) + (v - local);
        for (int i = i0; i < i1; ++i) {
            int d = agent_load_i(&degi[i]);
            row_ptr[i] = run;
            run += d;
            nrm[i] = rsqrtf(1.0f + (float)d);
        }
        if (tid == 0) row_ptr[N] = ws4[3];
        __syncthreads();                           // drains stores
        if (tid == 0) {
            __threadfence();                       // wbL2: row_ptr/nrm -> LLC
            __hip_atomic_store(&ctrl[2], MAGIC2, __ATOMIC_RELAXED, __HIP_MEMORY_SCOPE_AGENT);
        }
    } else {
        // ---- fill role ----
        if (tid == 0) spin_until(&ctrl[2], MAGIC2);
        __syncthreads();
        int i = (bx - fillBase) * 256 + tid;
        if (i < E) {
            int d = dstp[i];
            int s = srcp[i];
            int pos = row_ptr[d] + atomicAdd(&fillc[d], 1);
            int2 rec;
            rec.x = s;
            rec.y = __float_as_int(nrm[s] * nrm[d]);
            edges[pos] = rec;
        }
    }
}

// ---------------- GCN aggregate: XCD half-slice, chunked sub-waves, unroll-4 --
// blockIdx%8 -> XCD; half = bx&1 constant per XCD -> 2.5 MB hb slice L2-resident.
// Wave = one node-half; lanes 0-31 take edges [0,h0), lanes 32-63 [h0,len)
// (contiguous chunks). 4 gathers in flight per sub-wave (latency hiding).
__global__ __launch_bounds__(256) void agg_u4_kernel(const unsigned short* __restrict__ hb,
                                                     const int* __restrict__ row_ptr,
                                                     const int2* __restrict__ edges,
                                                     const float* __restrict__ nrm,
                                                     unsigned short* __restrict__ aggb, int N) {
    int bx = blockIdx.x;
    int half = bx & 1;
    int tid = threadIdx.x;
    int wave = tid >> 6;
    int lane = tid & 63;
    int sub = lane >> 5;
    int sl = lane & 31;
    int n = (bx >> 1) * 4 + wave;
    if (n >= N) return;
    int c = half * 128 + sl * 4;
    const unsigned short* hbc = hb + c;
    int s = row_ptr[n], e = row_ptr[n + 1];
    int len = e - s;
    int h0 = (len + 1) >> 1;
    int base = s + sub * h0;
    int cnt = sub ? (len - h0) : h0;
    float a0 = 0.f, a1 = 0.f, a2 = 0.f, a3 = 0.f;
    int it = 0;
    for (; it + 3 < cnt; it += 4) {
        int2 e0 = edges[base + it];
        int2 e1 = edges[base + it + 1];
        int2 e2 = edges[base + it + 2];
        int2 e3 = edges[base + it + 3];
        ushort4 u0 = *(const ushort4*)&hbc[(size_t)e0.x * HID];
        ushort4 u1 = *(const ushort4*)&hbc[(size_t)e1.x * HID];
        ushort4 u2 = *(const ushort4*)&hbc[(size_t)e2.x * HID];
        ushort4 u3 = *(const ushort4*)&hbc[(size_t)e3.x * HID];
        float w0 = __int_as_float(e0.y), w1 = __int_as_float(e1.y);
        float w2 = __int_as_float(e2.y), w3 = __int_as_float(e3.y);
        a0 += w0 * bf2f(u0.x) + w1 * bf2f(u1.x) + w2 * bf2f(u2.x) + w3 * bf2f(u3.x);
        a1 += w0 * bf2f(u0.y) + w1 * bf2f(u1.y) + w2 * bf2f(u2.y) + w3 * bf2f(u3.y);
        a2 += w0 * bf2f(u0.z) + w1 * bf2f(u1.z) + w2 * bf2f(u2.z) + w3 * bf2f(u3.z);
        a3 += w0 * bf2f(u0.w) + w1 * bf2f(u1.w) + w2 * bf2f(u2.w) + w3 * bf2f(u3.w);
    }
    for (; it < cnt; ++it) {
        int2 e0 = edges[base + it];
        ushort4 u0 = *(const ushort4*)&hbc[(size_t)e0.x * HID];
        float w0 = __int_as_float(e0.y);
        a0 += w0 * bf2f(u0.x);
        a1 += w0 * bf2f(u0.y);
        a2 += w0 * bf2f(u0.z);
        a3 += w0 * bf2f(u0.w);
    }
    a0 += __shfl_xor(a0, 32);
    a1 += __shfl_xor(a1, 32);
    a2 += __shfl_xor(a2, 32);
    a3 += __shfl_xor(a3, 32);
    if (sub == 0) {
        float nd = nrm[n];
        float swt = nd * nd;
        ushort4 us = *(const ushort4*)&hbc[(size_t)n * HID];
        a0 += swt * bf2f(us.x);
        a1 += swt * bf2f(us.y);
        a2 += swt * bf2f(us.z);
        a3 += swt * bf2f(us.w);
        ushort4 o;
        o.x = f2bf(a0); o.y = f2bf(a1); o.z = f2bf(a2); o.w = f2bf(a3);
        *(ushort4*)&aggb[(size_t)n * HID + c] = o;
    }
}

// ---------------- bf16 MFMA GEMM + bias + fused BN column stats ----------------
__global__ __launch_bounds__(256) void mfma_gemm(const unsigned short* __restrict__ A,
                                                 const unsigned short* __restrict__ Bt,
                                                 const float* __restrict__ bias,
                                                 unsigned short* __restrict__ C,
                                                 float* __restrict__ sums, int M) {
    __shared__ unsigned short As[64][40];
    __shared__ unsigned short Bs[64][40];
    __shared__ float lsum[64];
    __shared__ float lsq[64];
    int tid = threadIdx.x;
    int row0 = blockIdx.x * 64;
    int col0 = blockIdx.y * 64;
    int lrow = tid >> 2;
    int lkc = (tid & 3) * 8;
    int lane = tid & 63;
    int wid = tid >> 6;
    int wm = (wid & 1) * 32;
    int wn = (wid >> 1) * 32;
    int quad = lane >> 4;
    int ln = lane & 15;

    floatx4 acc00 = {0.f, 0.f, 0.f, 0.f};
    floatx4 acc01 = {0.f, 0.f, 0.f, 0.f};
    floatx4 acc10 = {0.f, 0.f, 0.f, 0.f};
    floatx4 acc11 = {0.f, 0.f, 0.f, 0.f};

    if (tid < 64) { lsum[tid] = 0.f; lsq[tid] = 0.f; }

    for (int kk = 0; kk < HID; kk += 32) {
        short8 av = {0, 0, 0, 0, 0, 0, 0, 0};
        int ar = row0 + lrow;
        if (ar < M) av = *(const short8*)&A[(size_t)ar * HID + kk + lkc];
        short8 bv = *(const short8*)&Bt[(size_t)(col0 + lrow) * HID + kk + lkc];
        *(short8*)&As[lrow][lkc] = av;
        *(short8*)&Bs[lrow][lkc] = bv;
        __syncthreads();
        short8 a0 = *(const short8*)&As[wm + ln][quad * 8];
        short8 a1 = *(const short8*)&As[wm + 16 + ln][quad * 8];
        short8 b0 = *(const short8*)&Bs[wn + ln][quad * 8];
        short8 b1 = *(const short8*)&Bs[wn + 16 + ln][quad * 8];
        acc00 = __builtin_amdgcn_mfma_f32_16x16x32_bf16(a0, b0, acc00, 0, 0, 0);
        acc01 = __builtin_amdgcn_mfma_f32_16x16x32_bf16(a0, b1, acc01, 0, 0, 0);
        acc10 = __builtin_amdgcn_mfma_f32_16x16x32_bf16(a1, b0, acc10, 0, 0, 0);
        acc11 = __builtin_amdgcn_mfma_f32_16x16x32_bf16(a1, b1, acc11, 0, 0, 0);
        __syncthreads();
    }
    float bias0 = bias[col0 + wn + ln];
    float bias1 = bias[col0 + wn + 16 + ln];
    float p0 = 0.f, q0 = 0.f, p1 = 0.f, q1 = 0.f;
#pragma unroll
    for (int r = 0; r < 4; ++r) {
        int row = row0 + wm + quad * 4 + r;
        if (row < M) {
            float v0 = acc00[r] + bias0;
            float v1 = acc01[r] + bias1;
            C[(size_t)row * HID + col0 + wn + ln] = f2bf(v0);
            C[(size_t)row * HID + col0 + wn + 16 + ln] = f2bf(v1);
            p0 += v0; q0 += v0 * v0;
            p1 += v1; q1 += v1 * v1;
        }
        int row2 = row + 16;
        if (row2 < M) {
            float v0 = acc10[r] + bias0;
            float v1 = acc11[r] + bias1;
            C[(size_t)row2 * HID + col0 + wn + ln] = f2bf(v0);
            C[(size_t)row2 * HID + col0 + wn + 16 + ln] = f2bf(v1);
            p0 += v0; q0 += v0 * v0;
            p1 += v1; q1 += v1 * v1;
        }
    }
    atomicAdd(&lsum[wn + ln], p0);
    atomicAdd(&lsq[wn + ln], q0);
    atomicAdd(&lsum[wn + 16 + ln], p1);
    atomicAdd(&lsq[wn + 16 + ln], q1);
    __syncthreads();
    if (tid < 64) {
        unsafeAtomicAdd(&sums[col0 + tid], lsum[tid]);
        unsafeAtomicAdd(&sums[HID + col0 + tid], lsq[tid]);
    }
}

// ---------------- BN apply + relu + residual, all bf16 ------------------------
__global__ __launch_bounds__(256) void bn_kernel(const unsigned short* __restrict__ hwb,
                                                 const float* __restrict__ sums,
                                                 const float* __restrict__ gamma,
                                                 const float* __restrict__ beta,
                                                 const unsigned short* __restrict__ hold,
                                                 unsigned short* __restrict__ hbnew, int N) {
    int i4 = blockIdx.x * blockDim.x + threadIdx.x;
    int base = i4 * 4;
    if (base >= N * HID) return;
    int c = base & (HID - 1);
    float invN = 1.0f / (float)N;
    float4 s4 = *(const float4*)&sums[c];
    float4 q4 = *(const float4*)&sums[HID + c];
    float4 g4 = *(const float4*)&gamma[c];
    float4 be4 = *(const float4*)&beta[c];
    ushort4 v = *(const ushort4*)&hwb[base];
    ushort4 r = *(const ushort4*)&hold[base];
    ushort4 o;
    {
        float mu = s4.x * invN, var = q4.x * invN - mu * mu;
        o.x = f2bf(fmaxf((bf2f(v.x) - mu) * g4.x * rsqrtf(var + BN_EPS) + be4.x, 0.f) + bf2f(r.x));
        mu = s4.y * invN; var = q4.y * invN - mu * mu;
        o.y = f2bf(fmaxf((bf2f(v.y) - mu) * g4.y * rsqrtf(var + BN_EPS) + be4.y, 0.f) + bf2f(r.y));
        mu = s4.z * invN; var = q4.z * invN - mu * mu;
        o.z = f2bf(fmaxf((bf2f(v.z) - mu) * g4.z * rsqrtf(var + BN_EPS) + be4.z, 0.f) + bf2f(r.z));
        mu = s4.w * invN; var = q4.w * invN - mu * mu;
        o.w = f2bf(fmaxf((bf2f(v.w) - mu) * g4.w * rsqrtf(var + BN_EPS) + be4.w, 0.f) + bf2f(r.w));
    }
    *(ushort4*)&hbnew[base] = o;
}

// ---------------- fused mean-pool (binary search on sorted batch) + MLP -------
__device__ inline int lower_bound_g(const int* __restrict__ a, int n, int key) {
    int lo = 0, hi = n;
    while (lo < hi) {
        int mid = (lo + hi) >> 1;
        if (a[mid] < key) lo = mid + 1; else hi = mid;
    }
    return lo;
}

__global__ __launch_bounds__(256) void pool_mlp_kernel(const unsigned short* __restrict__ h,
                                                       const int* __restrict__ batch, int N,
                                                       const float* __restrict__ W1,
                                                       const float* __restrict__ b1,
                                                       const float* __restrict__ W2,
                                                       const float* __restrict__ b2,
                                                       const float* __restrict__ W3,
                                                       const float* __restrict__ b3,
                                                       float* __restrict__ out) {
    int g = blockIdx.x, tid = threadIdx.x;
    int lo = lower_bound_g(batch, N, g);
    int hi = lower_bound_g(batch, N, g + 1);
    float s = 0.f;
    for (int i = lo; i < hi; ++i) s += bf2f(h[(size_t)i * HID + tid]);
    __shared__ float gs[256];
    __shared__ float t1[128];
    __shared__ float t2[64];
    float inv = 1.0f / fmaxf((float)(hi - lo), 1.0f);
    gs[tid] = s * inv;
    __syncthreads();
    if (tid < 128) {
        float a = b1[tid];
        for (int k = 0; k < 256; ++k) a += gs[k] * W1[k * 128 + tid];
        t1[tid] = fmaxf(a, 0.f);
    }
    __syncthreads();
    if (tid < 64) {
        float a = b2[tid];
        for (int k = 0; k < 128; ++k) a += t1[k] * W2[k * 64 + tid];
        t2[tid] = fmaxf(a, 0.f);
    }
    __syncthreads();
    if (tid < 64) {
        float p = t2[tid] * W3[tid];
#pragma unroll
        for (int off = 32; off >= 1; off >>= 1) p += __shfl_down(p, off);
        if (tid == 0) out[g] = p + b3[0];
    }
}

extern "C" void kernel_launch(void* const* d_in, const int* in_sizes, int n_in,
                              void* d_out, int out_size, void* d_ws, size_t ws_size,
                              hipStream_t stream) {
    const int* x      = (const int*)d_in[0];
    const int* ei     = (const int*)d_in[1];
    const int* batch  = (const int*)d_in[2];
    const float* emb  = (const float*)d_in[3];
    const float* W    = (const float*)d_in[4];
    const float* b    = (const float*)d_in[5];
    const float* gamma= (const float*)d_in[6];
    const float* beta = (const float*)d_in[7];
    const float* W1   = (const float*)d_in[8];
    const float* b1   = (const float*)d_in[9];
    const float* W2   = (const float*)d_in[10];
    const float* b2   = (const float*)d_in[11];
    const float* W3   = (const float*)d_in[12];
    const float* b3   = (const float*)d_in[13];
    float* out = (float*)d_out;

    int N = in_sizes[0] / NFEAT;
    int E = in_sizes[1] / 2;

    char* ws = (char*)d_ws;
    auto alloc = [&](size_t bytes) -> char* {
        char* p = ws;
        ws += (bytes + 255) & ~(size_t)255;
        return p;
    };
    unsigned int* ctrl = (unsigned int*)alloc(256);   // [0]=ready [1]=deg_done [2]=scan_flag
    int* degi     = (int*)alloc((size_t)N * 4);
    int* row_ptr  = (int*)alloc((size_t)(N + 1) * 4);
    int* fillc    = (int*)alloc((size_t)N * 4);
    float* nrm    = (float*)alloc((size_t)N * 4);
    int2* edges   = (int2*)alloc((size_t)E * 8);
    unsigned short* hbA  = (unsigned short*)alloc((size_t)N * HID * 2);
    unsigned short* hbB  = (unsigned short*)alloc((size_t)N * HID * 2);
    unsigned short* aggb = (unsigned short*)alloc((size_t)N * HID * 2);
    unsigned short* hwb  = (unsigned short*)alloc((size_t)N * HID * 2);
    unsigned short* wt   = (unsigned short*)alloc((size_t)NLAYERS * HID * HID * 2);
    float* bnsums = (float*)alloc((size_t)NLAYERS * 2 * HID * 4);

    // ctrl must not hold MAGIC values from a previous call's state: ws is
    // re-poisoned to 0xAA by the harness before every timed launch, so ctrl
    // always starts at 0xAAAAAAAA != MAGIC1/MAGIC2. But for the first
    // (correctness) call sequence safety, clear asynchronously:
    hipMemsetAsync(ctrl, 0, 256, stream);

    int nbDeg = (E + 255) / 256;
    int wcvtBase = 1 + nbDeg;
    int embBase = wcvtBase + 256;
    int scanIdx = embBase + N;
    int fillBase = scanIdx + 1;
    int megaGrid = fillBase + nbDeg;

    mega_setup<<<megaGrid, 256, 0, stream>>>(x, ei, emb, W, ctrl, degi, row_ptr,
                                             fillc, nrm, edges, wt, hbA, bnsums,
                                             N, E, nbDeg, wcvtBase, embBase, scanIdx, fillBase);

    unsigned short* hbcur = hbA;
    unsigned short* hboth = hbB;
    int aggGrid = ((N + 3) / 4) * 2;
    for (int l = 0; l < NLAYERS; ++l) {
        float* lsums = bnsums + (size_t)l * 2 * HID;
        agg_u4_kernel<<<aggGrid, 256, 0, stream>>>(hbcur, row_ptr, edges, nrm, aggb, N);
        dim3 ggrid((N + 63) / 64, 4);
        mfma_gemm<<<ggrid, 256, 0, stream>>>(aggb, wt + (size_t)l * HID * HID,
                                             b + (size_t)l * HID, hwb, lsums, N);
        bn_kernel<<<((size_t)N * HID / 4 + 255) / 256, 256, 0, stream>>>(
            hwb, lsums, gamma + (size_t)l * HID, beta + (size_t)l * HID,
            hbcur, hboth, N);
        unsigned short* tb = hbcur; hbcur = hboth; hboth = tb;
    }

    pool_mlp_kernel<<<NGRAPHS, 256, 0, stream>>>(hbcur, batch, N, W1, b1, W2, b2, W3, b3, out);
}